// Round 4
// baseline (346.505 us; speedup 1.0000x reference)
//
#include <hip/hip_runtime.h>

// IPA forward, MI355X. B=2,N=512,C_S=384,C_Z=128,H=12,D=16,PQ=4,PV=8,OUT_IN=2112.
// R3: 5a reads z A-frags directly from global (no LDS transpose, no barriers),
//     softmax writes attnb directly (deferred rinv), barriers 21->5.

typedef __attribute__((ext_vector_type(8))) short bf16x8;
typedef __attribute__((ext_vector_type(4))) float f32x4;

__device__ __forceinline__ unsigned short f2b(float f) {
  union { float f; unsigned int u; } x; x.f = f;
  unsigned int r = (x.u + 0x7FFFu + ((x.u >> 16) & 1u)) >> 16;
  return (unsigned short)r;
}

// ---------------- K0: wout (2112x384 f32) -> woutT (384x2112 bf16) ----------------
__global__ __launch_bounds__(256) void k_woutT(const float* __restrict__ wout,
                                               unsigned short* __restrict__ woutT) {
  __shared__ float tile[32][33];
  int kb = blockIdx.x * 32, cb = blockIdx.y * 32;
  int tx = threadIdx.x & 31, ty = threadIdx.x >> 5;
  #pragma unroll
  for (int r = ty; r < 32; r += 8) tile[r][tx] = wout[(size_t)(kb + r) * 384 + cb + tx];
  __syncthreads();
  #pragma unroll
  for (int r = ty; r < 32; r += 8) woutT[(size_t)(cb + r) * 2112 + kb + tx] = f2b(tile[tx][r]);
}

// ---------------- K1: projections + global-frame points (transposed outputs) ----------------
__global__ __launch_bounds__(512) void k_proj(
    const float* __restrict__ s,
    const float* __restrict__ wq, const float* __restrict__ bq,
    const float* __restrict__ wkv, const float* __restrict__ bkv,
    const float* __restrict__ wqp, const float* __restrict__ bqp,
    const float* __restrict__ wkvp, const float* __restrict__ bkvp,
    const float* __restrict__ rot, const float* __restrict__ trn,
    float* __restrict__ qws, float* __restrict__ qgws,
    float* __restrict__ kT, float* __restrict__ kgT,
    unsigned short* __restrict__ vT) {
  __shared__ float s_lds[4 * 384];
  __shared__ float praw[4][576];
  int tid = threadIdx.x;
  int row0 = blockIdx.x * 4;

  for (int idx = tid; idx < 1536; idx += 512)
    s_lds[idx] = s[(size_t)row0 * 384 + idx];
  __syncthreads();

  int no = 0;
  const float* wpt[3]; int stv[3]; float acc[3][4];
  int ocol[3];
  for (int o = tid; o < 1152; o += 512) {
    const float* w; float bias; int ncol, col;
    if (o < 192)      { w = wq;   ncol = 192; col = o;       bias = bq[col]; }
    else if (o < 576) { w = wkv;  ncol = 384; col = o - 192; bias = bkv[col]; }
    else if (o < 720) { w = wqp;  ncol = 144; col = o - 576; bias = bqp[col]; }
    else              { w = wkvp; ncol = 432; col = o - 720; bias = bkvp[col]; }
    wpt[no] = w + col; stv[no] = ncol; ocol[no] = o;
    acc[no][0] = bias; acc[no][1] = bias; acc[no][2] = bias; acc[no][3] = bias;
    no++;
  }

  for (int kc = 0; kc < 384; kc += 8) {
    float sreg[4][8];
    #pragma unroll
    for (int r = 0; r < 4; r++) {
      float4 a = *(const float4*)&s_lds[r * 384 + kc];
      float4 b = *(const float4*)&s_lds[r * 384 + kc + 4];
      sreg[r][0] = a.x; sreg[r][1] = a.y; sreg[r][2] = a.z; sreg[r][3] = a.w;
      sreg[r][4] = b.x; sreg[r][5] = b.y; sreg[r][6] = b.z; sreg[r][7] = b.w;
    }
    for (int oi = 0; oi < no; oi++) {
      const float* wcp = wpt[oi]; int st = stv[oi];
      #pragma unroll
      for (int e = 0; e < 8; e++) {
        float wv = wcp[(size_t)(kc + e) * st];
        #pragma unroll
        for (int r = 0; r < 4; r++) acc[oi][r] += sreg[r][e] * wv;
      }
    }
  }

  for (int oi = 0; oi < no; oi++) {
    int o = ocol[oi];
    #pragma unroll
    for (int r = 0; r < 4; r++) {
      float v = acc[oi][r];
      int bi = row0 + r;
      int bb2 = bi >> 9, jj = bi & 511;
      if (o < 192) qws[(size_t)bi * 192 + o] = v;
      else if (o < 576) {
        int c = o - 192, h = c >> 5, e = c & 31;
        if (e < 16) kT[((size_t)bb2 * 192 + h * 16 + e) * 512 + jj] = v;
        else        vT[((size_t)bb2 * 480 + h * 16 + (e - 16)) * 512 + jj] = f2b(v);
      } else praw[r][o - 576] = v;
    }
  }
  __syncthreads();

  for (int idx = tid; idx < 768; idx += 512) {
    int r = idx / 192, p = idx % 192;
    int bi = row0 + r;
    int bb2 = bi >> 9, jj = bi & 511;
    const float* Rm = rot + (size_t)bi * 9;
    const float* tv = trn + (size_t)bi * 3;
    float x, y, z;
    if (p < 48) { x = praw[r][p]; y = praw[r][48 + p]; z = praw[r][96 + p]; }
    else { int q = p - 48; x = praw[r][144 + q]; y = praw[r][288 + q]; z = praw[r][432 + q]; }
    float gx = Rm[0] * x + Rm[1] * y + Rm[2] * z + tv[0];
    float gy = Rm[3] * x + Rm[4] * y + Rm[5] * z + tv[1];
    float gz = Rm[6] * x + Rm[7] * y + Rm[8] * z + tv[2];
    if (p < 48) {
      float* dst = qgws + (size_t)bi * 144 + p * 3;
      dst[0] = gx; dst[1] = gy; dst[2] = gz;
    } else {
      int q12 = p - 48; int h = q12 / 12, qq = q12 % 12;
      if (qq < 4) {
        size_t base = ((size_t)bb2 * 144 + h * 12 + qq * 3) * 512 + jj;
        kgT[base] = gx; kgT[base + 512] = gy; kgT[base + 1024] = gz;
      } else {
        size_t base = ((size_t)bb2 * 480 + 192 + h * 24 + (qq - 4) * 3) * 512 + jj;
        vT[base] = f2b(gx); vT[base + 512] = f2b(gy); vT[base + 1024] = f2b(gz);
      }
    }
  }
}

// ---------------- K2: fused attention per (b,i) ----------------
__global__ __launch_bounds__(512, 6) void k_attn(
    const float* __restrict__ z, const float* __restrict__ mrow,
    const float* __restrict__ rot, const float* __restrict__ trn,
    const float* __restrict__ hwt, const float* __restrict__ wb, const float* __restrict__ bb,
    const float* __restrict__ qws, const float* __restrict__ qgws,
    const float* __restrict__ kT, const float* __restrict__ kgT,
    const unsigned short* __restrict__ vT,
    unsigned short* __restrict__ feats) {
  __shared__ float logits[12][512];          // 24KB (pre-softmax only)
  __shared__ unsigned short attnb[8192];     // 16KB, swizzled [16][512] bf16 (rows 12-15 zero)
  __shared__ unsigned short wbT[16][128];    // 4KB
  __shared__ float q_lds[192], qg_lds[144], rpg_lds[288];
  __shared__ float rinv[12], hwc[12], Rl[9], tl[3], bbl[16];
  __shared__ float m_i_sh;

  int tid = threadIdx.x;
  int bi = blockIdx.x;
  int b = bi >> 9;
  const float* zbase = z + (size_t)bi * 512 * 128;
  int wv = tid >> 6, l = tid & 63, lr = l & 15, lk = l >> 4;

  // phase 0: stage per-i data; zero attnb rows 12..15
  if (tid < 192) q_lds[tid] = qws[(size_t)bi * 192 + tid];
  else if (tid < 336) qg_lds[tid - 192] = qgws[(size_t)bi * 144 + (tid - 192)];
  else if (tid < 348) {
    int h = tid - 336; float w = hwt[h];
    hwc[h] = 0.5f * logf(1.0f + __expf(w)) * 0.13608276348795434f; // 0.5*softplus*sqrt(1/54)
  }
  else if (tid >= 352 && tid < 361) Rl[tid - 352] = rot[(size_t)bi * 9 + (tid - 352)];
  else if (tid >= 364 && tid < 367) tl[tid - 364] = trn[(size_t)bi * 3 + (tid - 364)];
  else if (tid >= 368 && tid < 384) bbl[tid - 368] = ((tid - 368) < 12) ? bb[tid - 368] : 0.0f;
  else if (tid == 384) m_i_sh = mrow[bi];
  for (int idx = tid; idx < 2048; idx += 512) {
    int h = idx >> 7, c = idx & 127;
    wbT[h][c] = (h < 12) ? f2b(wb[c * 12 + h]) : (unsigned short)0;
  }
  { // zero rows 12..15 of attnb (4 x 512 u16 = 2048 u16); 512 threads x 4
    ushort4 zer = {0, 0, 0, 0};
    int h = 12 + (tid >> 7), j4 = (tid & 127) * 4;
    int byte = (h * 1024 + j4 * 2) ^ ((h & 7) << 4);
    *(ushort4*)((char*)attnb + byte) = zer;
  }
  __syncthreads();

  // phase 1: bias MFMA. logits[h][j] = sqrt(1/3)*(z_row . wb_col + bb)
  {
    bf16x8 bfrag[4];
    #pragma unroll
    for (int kc = 0; kc < 4; kc++)
      bfrag[kc] = *(const bf16x8*)&wbT[lr][kc * 32 + lk * 8];
    #pragma unroll 2
    for (int jt = wv; jt < 32; jt += 8) {
      f32x4 acc = {0.f, 0.f, 0.f, 0.f};
      const float4* z4 = (const float4*)(zbase + (size_t)(jt * 16 + lr) * 128);
      #pragma unroll
      for (int kc = 0; kc < 4; kc++) {
        float4 a0 = z4[kc * 8 + lk * 2 + 0];
        float4 a1 = z4[kc * 8 + lk * 2 + 1];
        bf16x8 afrag;
        afrag[0] = (short)f2b(a0.x); afrag[1] = (short)f2b(a0.y);
        afrag[2] = (short)f2b(a0.z); afrag[3] = (short)f2b(a0.w);
        afrag[4] = (short)f2b(a1.x); afrag[5] = (short)f2b(a1.y);
        afrag[6] = (short)f2b(a1.z); afrag[7] = (short)f2b(a1.w);
        acc = __builtin_amdgcn_mfma_f32_16x16x32_bf16(afrag, bfrag[kc], acc, 0, 0, 0);
      }
      if (lr < 12) {
        #pragma unroll
        for (int reg = 0; reg < 4; reg++) {
          int j = jt * 16 + lk * 4 + reg;
          logits[lr][j] = 0.5773502691896258f * (acc[reg] + bbl[lr]);
        }
      }
    }
  }
  __syncthreads();

  // phase 2: += qk*sqrt(1/48) - 0.5*hw*pa + mask. one thread per j, coalesced transposed reads.
  {
    int j = tid;
    const float* kTb  = kT  + (size_t)b * 192 * 512 + j;
    const float* kgTb = kgT + (size_t)b * 144 * 512 + j;
    float mj = mrow[b * 512 + j];
    float mterm = 100000.0f * (m_i_sh * mj - 1.0f);
    #pragma unroll 2
    for (int h = 0; h < 12; h++) {
      float qk = 0.f;
      #pragma unroll
      for (int d = 0; d < 16; d++) qk += q_lds[h * 16 + d] * kTb[(size_t)(h * 16 + d) * 512];
      float pa = 0.f;
      #pragma unroll
      for (int pc = 0; pc < 12; pc++) {
        float diff = qg_lds[h * 12 + pc] - kgTb[(size_t)(h * 12 + pc) * 512];
        pa += diff * diff;
      }
      logits[h][j] += qk * 0.14433756729740643f - hwc[h] * pa + mterm;
    }
  }
  __syncthreads();

  // phase 3: softmax per h (32 lanes per h); write exp (unnormalized) to attnb bf16; rinv[h]=1/sum
  if (tid < 384) {
    int h = tid >> 5, g = tid & 31;
    float4 vals[4];
    float mx = -1e30f;
    #pragma unroll
    for (int it = 0; it < 4; it++) {
      vals[it] = *(const float4*)&logits[h][it * 128 + g * 4];
      mx = fmaxf(mx, fmaxf(fmaxf(vals[it].x, vals[it].y), fmaxf(vals[it].z, vals[it].w)));
    }
    #pragma unroll
    for (int off = 16; off > 0; off >>= 1) mx = fmaxf(mx, __shfl_xor(mx, off, 32));
    float sum = 0.f;
    #pragma unroll
    for (int it = 0; it < 4; it++) {
      float4 e;
      e.x = __expf(vals[it].x - mx); e.y = __expf(vals[it].y - mx);
      e.z = __expf(vals[it].z - mx); e.w = __expf(vals[it].w - mx);
      sum += e.x + e.y + e.z + e.w;
      ushort4 ob;
      ob.x = f2b(e.x); ob.y = f2b(e.y); ob.z = f2b(e.z); ob.w = f2b(e.w);
      int j4 = it * 128 + g * 4;
      int byte = (h * 1024 + j4 * 2) ^ ((h & 7) << 4);
      *(ushort4*)((char*)attnb + byte) = ob;
    }
    #pragma unroll
    for (int off = 16; off > 0; off >>= 1) sum += __shfl_xor(sum, off, 32);
    if (g == 0) rinv[h] = 1.0f / sum;
  }
  __syncthreads();

  size_t fb = (size_t)bi * 2112;

  // phase 5a: out_pair^T = z^T @ p^T via MFMA; A-frags loaded directly from global z
  // (L3-hit second pass), coalesced 64B segments, no LDS staging, no barriers.
  {
    int c0w = wv * 16;
    const float* zcol = zbase + c0w + lr;   // z[j][c]: element j*128 + c0w+lr
    f32x4 acc = {0.f, 0.f, 0.f, 0.f};
    #pragma unroll 2
    for (int jt = 0; jt < 16; jt++) {
      int jb = jt * 32 + lk * 8;
      const float* zj = zcol + (size_t)jb * 128;
      float a0 = zj[0];
      float a1 = zj[128];
      float a2 = zj[256];
      float a3 = zj[384];
      float a4 = zj[512];
      float a5 = zj[640];
      float a6 = zj[768];
      float a7 = zj[896];
      bf16x8 afrag;
      afrag[0] = (short)f2b(a0); afrag[1] = (short)f2b(a1);
      afrag[2] = (short)f2b(a2); afrag[3] = (short)f2b(a3);
      afrag[4] = (short)f2b(a4); afrag[5] = (short)f2b(a5);
      afrag[6] = (short)f2b(a6); afrag[7] = (short)f2b(a7);
      int abyte = (lr * 1024 + jb * 2) ^ ((lr & 7) << 4);
      bf16x8 pfrag = *(const bf16x8*)((const char*)attnb + abyte);
      acc = __builtin_amdgcn_mfma_f32_16x16x32_bf16(afrag, pfrag, acc, 0, 0, 0);
    }
    if (lr < 12) {
      float rn = rinv[lr];
      ushort4 ow;
      ow.x = f2b(acc[0] * rn); ow.y = f2b(acc[1] * rn);
      ow.z = f2b(acc[2] * rn); ow.w = f2b(acc[3] * rn);
      *(ushort4*)&feats[fb + 576 + lr * 128 + c0w + lk * 4] = ow;
    }
  }

  // phase 5b: [out_scalar | rpg] = attn @ [v | vg] via MFMA over vT (L2-resident), deferred rinv
  {
    const unsigned short* vTb = vT + (size_t)b * 480 * 512;
    for (int t = wv; t < 30; t += 8) {
      int c0 = t * 16;
      const unsigned short* vrow = vTb + (size_t)(c0 + lr) * 512 + lk * 8;
      f32x4 acc = {0.f, 0.f, 0.f, 0.f};
      #pragma unroll
      for (int kc = 0; kc < 16; kc++) {
        bf16x8 bfrag = *(const bf16x8*)(vrow + kc * 32);
        int abyte = (lr * 1024 + (kc * 32 + lk * 8) * 2) ^ ((lr & 7) << 4);
        bf16x8 afrag = *(const bf16x8*)((const char*)attnb + abyte);
        acc = __builtin_amdgcn_mfma_f32_16x16x32_bf16(afrag, bfrag, acc, 0, 0, 0);
      }
      #pragma unroll
      for (int reg = 0; reg < 4; reg++) {
        int h = lk * 4 + reg;
        if (h < 12) {
          float val = acc[reg] * rinv[h];
          int c = c0 + lr;
          if (c < 192) { if ((c >> 4) == h) feats[fb + c] = f2b(val); }
          else { int r = c - 192; if (r >= h * 24 && r < h * 24 + 24) rpg_lds[r] = val; }
        }
      }
    }
  }
  __syncthreads();

  // phase 6: rpl = R^T (rpg - t), norms
  if (tid < 96) {
    int h = tid >> 3, pv = tid & 7;
    float gx = rpg_lds[h * 24 + pv * 3 + 0] - tl[0];
    float gy = rpg_lds[h * 24 + pv * 3 + 1] - tl[1];
    float gz = rpg_lds[h * 24 + pv * 3 + 2] - tl[2];
    float lx = Rl[0] * gx + Rl[3] * gy + Rl[6] * gz;
    float ly = Rl[1] * gx + Rl[4] * gy + Rl[7] * gz;
    float lz = Rl[2] * gx + Rl[5] * gy + Rl[8] * gz;
    feats[fb + 192 + tid] = f2b(lx);
    feats[fb + 288 + tid] = f2b(ly);
    feats[fb + 384 + tid] = f2b(lz);
    feats[fb + 480 + tid] = f2b(sqrtf(lx * lx + ly * ly + lz * lz + 1e-8f));
  }
}

// ---------------- K3: out = (feats @ wout + bout) * mask ----------------
__global__ __launch_bounds__(256) void k_out(const unsigned short* __restrict__ feats,
                                             const unsigned short* __restrict__ woutT,
                                             const float* __restrict__ bout,
                                             const float* __restrict__ mrow,
                                             float* __restrict__ out) {
  __shared__ unsigned short At[2048]; // [64 m][32 k] bf16 swizzled
  __shared__ unsigned short Bt[2048]; // [64 n][32 k] bf16 swizzled
  int m0 = blockIdx.x * 64, n0 = blockIdx.y * 64;
  int tid = threadIdx.x;
  int wv = tid >> 6, l = tid & 63, lr = l & 15, lk = l >> 4;
  int wm = wv >> 1, wn = wv & 1;
  f32x4 acc[2][2] = {};
  int sr = tid >> 2, sq = tid & 3;
  const char* fbase = (const char*)feats + (size_t)(m0 + sr) * 4224 + sq * 16;
  const char* bbase = (const char*)woutT + (size_t)(n0 + sr) * 4224 + sq * 16;
  int sw = ((sr * 64 + sq * 16) ^ ((sr & 7) << 4));

  uint4 av = *(const uint4*)(fbase);
  uint4 bv = *(const uint4*)(bbase);
  for (int k0 = 0; k0 < 2112; k0 += 32) {
    __syncthreads();
    *(uint4*)((char*)At + sw) = av;
    *(uint4*)((char*)Bt + sw) = bv;
    __syncthreads();
    if (k0 + 32 < 2112) {
      av = *(const uint4*)(fbase + (size_t)(k0 + 32) * 2);
      bv = *(const uint4*)(bbase + (size_t)(k0 + 32) * 2);
    }
    bf16x8 af[2], bf[2];
    #pragma unroll
    for (int mt = 0; mt < 2; mt++) {
      int row = wm * 32 + mt * 16 + lr;
      af[mt] = *(const bf16x8*)((const char*)At + ((row * 64 + lk * 16) ^ ((row & 7) << 4)));
    }
    #pragma unroll
    for (int nt = 0; nt < 2; nt++) {
      int row = wn * 32 + nt * 16 + lr;
      bf[nt] = *(const bf16x8*)((const char*)Bt + ((row * 64 + lk * 16) ^ ((row & 7) << 4)));
    }
    #pragma unroll
    for (int mt = 0; mt < 2; mt++)
      #pragma unroll
      for (int nt = 0; nt < 2; nt++)
        acc[mt][nt] = __builtin_amdgcn_mfma_f32_16x16x32_bf16(af[mt], bf[nt], acc[mt][nt], 0, 0, 0);
  }

  #pragma unroll
  for (int mt = 0; mt < 2; mt++) {
    #pragma unroll
    for (int nt = 0; nt < 2; nt++) {
      int nc = n0 + wn * 32 + nt * 16 + lr;
      float bo = bout[nc];
      #pragma unroll
      for (int reg = 0; reg < 4; reg++) {
        int rowg = m0 + wm * 32 + mt * 16 + lk * 4 + reg;
        out[(size_t)rowg * 384 + nc] = (acc[mt][nt][reg] + bo) * mrow[rowg];
      }
    }
  }
}

extern "C" void kernel_launch(void* const* d_in, const int* in_sizes, int n_in,
                              void* d_out, int out_size, void* d_ws, size_t ws_size,
                              hipStream_t stream) {
  const float* s    = (const float*)d_in[0];
  const float* z    = (const float*)d_in[1];
  const float* rot  = (const float*)d_in[2];
  const float* trn  = (const float*)d_in[3];
  const float* msk  = (const float*)d_in[4];
  const float* wq   = (const float*)d_in[5];
  const float* bq   = (const float*)d_in[6];
  const float* wkv  = (const float*)d_in[7];
  const float* bkv  = (const float*)d_in[8];
  const float* wqp  = (const float*)d_in[9];
  const float* bqp  = (const float*)d_in[10];
  const float* wkvp = (const float*)d_in[11];
  const float* bkvp = (const float*)d_in[12];
  const float* wb   = (const float*)d_in[13];
  const float* bb   = (const float*)d_in[14];
  const float* wout = (const float*)d_in[15];
  const float* bout = (const float*)d_in[16];
  const float* hwt  = (const float*)d_in[17];

  float* qws  = (float*)d_ws;                       // 196608 f32
  float* qgws = qws + 196608;                       // 147456 f32
  float* kT   = qgws + 147456;                      // 196608 f32
  float* kgT  = kT + 196608;                        // 147456 f32
  unsigned short* vT    = (unsigned short*)(kgT + 147456);  // 491520 u16
  unsigned short* feats = vT + 491520;              // 2162688 u16
  unsigned short* woutT = feats + 2162688;          // 811008 u16
  float* out = (float*)d_out;

  k_woutT<<<dim3(66, 12), dim3(256), 0, stream>>>(wout, woutT);
  k_proj<<<dim3(256), dim3(512), 0, stream>>>(s, wq, bq, wkv, bkv, wqp, bqp, wkvp, bkvp,
                                              rot, trn, qws, qgws, kT, kgT, vT);
  k_attn<<<dim3(1024), dim3(512), 0, stream>>>(z, msk, rot, trn, hwt, wb, bb,
                                               qws, qgws, kT, kgT, vT, feats);
  k_out<<<dim3(16, 6), dim3(256), 0, stream>>>(feats, woutT, bout, msk, out);
}

// Round 5
// 314.231 us; speedup vs baseline: 1.1027x; 1.1027x over previous
//
#include <hip/hip_runtime.h>

// IPA forward, MI355X. B=2,N=512,C_S=384,C_Z=128,H=12,D=16,PQ=4,PV=8,OUT_IN=2112.
// R4: remove __launch_bounds__(512,6) reg-strangle from k_attn (was 40 VGPR + 40MB scratch spill
//     traffic per dispatch); otherwise identical to R3.

typedef __attribute__((ext_vector_type(8))) short bf16x8;
typedef __attribute__((ext_vector_type(4))) float f32x4;

__device__ __forceinline__ unsigned short f2b(float f) {
  union { float f; unsigned int u; } x; x.f = f;
  unsigned int r = (x.u + 0x7FFFu + ((x.u >> 16) & 1u)) >> 16;
  return (unsigned short)r;
}

// ---------------- K0: wout (2112x384 f32) -> woutT (384x2112 bf16) ----------------
__global__ __launch_bounds__(256) void k_woutT(const float* __restrict__ wout,
                                               unsigned short* __restrict__ woutT) {
  __shared__ float tile[32][33];
  int kb = blockIdx.x * 32, cb = blockIdx.y * 32;
  int tx = threadIdx.x & 31, ty = threadIdx.x >> 5;
  #pragma unroll
  for (int r = ty; r < 32; r += 8) tile[r][tx] = wout[(size_t)(kb + r) * 384 + cb + tx];
  __syncthreads();
  #pragma unroll
  for (int r = ty; r < 32; r += 8) woutT[(size_t)(cb + r) * 2112 + kb + tx] = f2b(tile[tx][r]);
}

// ---------------- K1: projections + global-frame points (transposed outputs) ----------------
__global__ __launch_bounds__(512) void k_proj(
    const float* __restrict__ s,
    const float* __restrict__ wq, const float* __restrict__ bq,
    const float* __restrict__ wkv, const float* __restrict__ bkv,
    const float* __restrict__ wqp, const float* __restrict__ bqp,
    const float* __restrict__ wkvp, const float* __restrict__ bkvp,
    const float* __restrict__ rot, const float* __restrict__ trn,
    float* __restrict__ qws, float* __restrict__ qgws,
    float* __restrict__ kT, float* __restrict__ kgT,
    unsigned short* __restrict__ vT) {
  __shared__ float s_lds[4 * 384];
  __shared__ float praw[4][576];
  int tid = threadIdx.x;
  int row0 = blockIdx.x * 4;

  for (int idx = tid; idx < 1536; idx += 512)
    s_lds[idx] = s[(size_t)row0 * 384 + idx];
  __syncthreads();

  int no = 0;
  const float* wpt[3]; int stv[3]; float acc[3][4];
  int ocol[3];
  for (int o = tid; o < 1152; o += 512) {
    const float* w; float bias; int ncol, col;
    if (o < 192)      { w = wq;   ncol = 192; col = o;       bias = bq[col]; }
    else if (o < 576) { w = wkv;  ncol = 384; col = o - 192; bias = bkv[col]; }
    else if (o < 720) { w = wqp;  ncol = 144; col = o - 576; bias = bqp[col]; }
    else              { w = wkvp; ncol = 432; col = o - 720; bias = bkvp[col]; }
    wpt[no] = w + col; stv[no] = ncol; ocol[no] = o;
    acc[no][0] = bias; acc[no][1] = bias; acc[no][2] = bias; acc[no][3] = bias;
    no++;
  }

  for (int kc = 0; kc < 384; kc += 8) {
    float sreg[4][8];
    #pragma unroll
    for (int r = 0; r < 4; r++) {
      float4 a = *(const float4*)&s_lds[r * 384 + kc];
      float4 b = *(const float4*)&s_lds[r * 384 + kc + 4];
      sreg[r][0] = a.x; sreg[r][1] = a.y; sreg[r][2] = a.z; sreg[r][3] = a.w;
      sreg[r][4] = b.x; sreg[r][5] = b.y; sreg[r][6] = b.z; sreg[r][7] = b.w;
    }
    for (int oi = 0; oi < no; oi++) {
      const float* wcp = wpt[oi]; int st = stv[oi];
      #pragma unroll
      for (int e = 0; e < 8; e++) {
        float wv = wcp[(size_t)(kc + e) * st];
        #pragma unroll
        for (int r = 0; r < 4; r++) acc[oi][r] += sreg[r][e] * wv;
      }
    }
  }

  for (int oi = 0; oi < no; oi++) {
    int o = ocol[oi];
    #pragma unroll
    for (int r = 0; r < 4; r++) {
      float v = acc[oi][r];
      int bi = row0 + r;
      int bb2 = bi >> 9, jj = bi & 511;
      if (o < 192) qws[(size_t)bi * 192 + o] = v;
      else if (o < 576) {
        int c = o - 192, h = c >> 5, e = c & 31;
        if (e < 16) kT[((size_t)bb2 * 192 + h * 16 + e) * 512 + jj] = v;
        else        vT[((size_t)bb2 * 480 + h * 16 + (e - 16)) * 512 + jj] = f2b(v);
      } else praw[r][o - 576] = v;
    }
  }
  __syncthreads();

  for (int idx = tid; idx < 768; idx += 512) {
    int r = idx / 192, p = idx % 192;
    int bi = row0 + r;
    int bb2 = bi >> 9, jj = bi & 511;
    const float* Rm = rot + (size_t)bi * 9;
    const float* tv = trn + (size_t)bi * 3;
    float x, y, z;
    if (p < 48) { x = praw[r][p]; y = praw[r][48 + p]; z = praw[r][96 + p]; }
    else { int q = p - 48; x = praw[r][144 + q]; y = praw[r][288 + q]; z = praw[r][432 + q]; }
    float gx = Rm[0] * x + Rm[1] * y + Rm[2] * z + tv[0];
    float gy = Rm[3] * x + Rm[4] * y + Rm[5] * z + tv[1];
    float gz = Rm[6] * x + Rm[7] * y + Rm[8] * z + tv[2];
    if (p < 48) {
      float* dst = qgws + (size_t)bi * 144 + p * 3;
      dst[0] = gx; dst[1] = gy; dst[2] = gz;
    } else {
      int q12 = p - 48; int h = q12 / 12, qq = q12 % 12;
      if (qq < 4) {
        size_t base = ((size_t)bb2 * 144 + h * 12 + qq * 3) * 512 + jj;
        kgT[base] = gx; kgT[base + 512] = gy; kgT[base + 1024] = gz;
      } else {
        size_t base = ((size_t)bb2 * 480 + 192 + h * 24 + (qq - 4) * 3) * 512 + jj;
        vT[base] = f2b(gx); vT[base + 512] = f2b(gy); vT[base + 1024] = f2b(gz);
      }
    }
  }
}

// ---------------- K2: fused attention per (b,i) ----------------
__global__ __launch_bounds__(512) void k_attn(
    const float* __restrict__ z, const float* __restrict__ mrow,
    const float* __restrict__ rot, const float* __restrict__ trn,
    const float* __restrict__ hwt, const float* __restrict__ wb, const float* __restrict__ bb,
    const float* __restrict__ qws, const float* __restrict__ qgws,
    const float* __restrict__ kT, const float* __restrict__ kgT,
    const unsigned short* __restrict__ vT,
    unsigned short* __restrict__ feats) {
  __shared__ float logits[12][512];          // 24KB (pre-softmax only)
  __shared__ unsigned short attnb[8192];     // 16KB, swizzled [16][512] bf16 (rows 12-15 zero)
  __shared__ unsigned short wbT[16][128];    // 4KB
  __shared__ float q_lds[192], qg_lds[144], rpg_lds[288];
  __shared__ float rinv[12], hwc[12], Rl[9], tl[3], bbl[16];
  __shared__ float m_i_sh;

  int tid = threadIdx.x;
  int bi = blockIdx.x;
  int b = bi >> 9;
  const float* zbase = z + (size_t)bi * 512 * 128;
  int wv = tid >> 6, l = tid & 63, lr = l & 15, lk = l >> 4;

  // phase 0: stage per-i data; zero attnb rows 12..15
  if (tid < 192) q_lds[tid] = qws[(size_t)bi * 192 + tid];
  else if (tid < 336) qg_lds[tid - 192] = qgws[(size_t)bi * 144 + (tid - 192)];
  else if (tid < 348) {
    int h = tid - 336; float w = hwt[h];
    hwc[h] = 0.5f * logf(1.0f + __expf(w)) * 0.13608276348795434f; // 0.5*softplus*sqrt(1/54)
  }
  else if (tid >= 352 && tid < 361) Rl[tid - 352] = rot[(size_t)bi * 9 + (tid - 352)];
  else if (tid >= 364 && tid < 367) tl[tid - 364] = trn[(size_t)bi * 3 + (tid - 364)];
  else if (tid >= 368 && tid < 384) bbl[tid - 368] = ((tid - 368) < 12) ? bb[tid - 368] : 0.0f;
  else if (tid == 384) m_i_sh = mrow[bi];
  for (int idx = tid; idx < 2048; idx += 512) {
    int h = idx >> 7, c = idx & 127;
    wbT[h][c] = (h < 12) ? f2b(wb[c * 12 + h]) : (unsigned short)0;
  }
  { // zero rows 12..15 of attnb
    ushort4 zer = {0, 0, 0, 0};
    int h = 12 + (tid >> 7), j4 = (tid & 127) * 4;
    int byte = (h * 1024 + j4 * 2) ^ ((h & 7) << 4);
    *(ushort4*)((char*)attnb + byte) = zer;
  }
  __syncthreads();

  // phase 1: bias MFMA. logits[h][j] = sqrt(1/3)*(z_row . wb_col + bb)
  {
    bf16x8 bfrag[4];
    #pragma unroll
    for (int kc = 0; kc < 4; kc++)
      bfrag[kc] = *(const bf16x8*)&wbT[lr][kc * 32 + lk * 8];
    #pragma unroll 2
    for (int jt = wv; jt < 32; jt += 8) {
      f32x4 acc = {0.f, 0.f, 0.f, 0.f};
      const float4* z4 = (const float4*)(zbase + (size_t)(jt * 16 + lr) * 128);
      #pragma unroll
      for (int kc = 0; kc < 4; kc++) {
        float4 a0 = z4[kc * 8 + lk * 2 + 0];
        float4 a1 = z4[kc * 8 + lk * 2 + 1];
        bf16x8 afrag;
        afrag[0] = (short)f2b(a0.x); afrag[1] = (short)f2b(a0.y);
        afrag[2] = (short)f2b(a0.z); afrag[3] = (short)f2b(a0.w);
        afrag[4] = (short)f2b(a1.x); afrag[5] = (short)f2b(a1.y);
        afrag[6] = (short)f2b(a1.z); afrag[7] = (short)f2b(a1.w);
        acc = __builtin_amdgcn_mfma_f32_16x16x32_bf16(afrag, bfrag[kc], acc, 0, 0, 0);
      }
      if (lr < 12) {
        #pragma unroll
        for (int reg = 0; reg < 4; reg++) {
          int j = jt * 16 + lk * 4 + reg;
          logits[lr][j] = 0.5773502691896258f * (acc[reg] + bbl[lr]);
        }
      }
    }
  }
  __syncthreads();

  // phase 2: += qk*sqrt(1/48) - 0.5*hw*pa + mask. one thread per j, coalesced transposed reads.
  {
    int j = tid;
    const float* kTb  = kT  + (size_t)b * 192 * 512 + j;
    const float* kgTb = kgT + (size_t)b * 144 * 512 + j;
    float mj = mrow[b * 512 + j];
    float mterm = 100000.0f * (m_i_sh * mj - 1.0f);
    #pragma unroll 2
    for (int h = 0; h < 12; h++) {
      float qk = 0.f;
      #pragma unroll
      for (int d = 0; d < 16; d++) qk += q_lds[h * 16 + d] * kTb[(size_t)(h * 16 + d) * 512];
      float pa = 0.f;
      #pragma unroll
      for (int pc = 0; pc < 12; pc++) {
        float diff = qg_lds[h * 12 + pc] - kgTb[(size_t)(h * 12 + pc) * 512];
        pa += diff * diff;
      }
      logits[h][j] += qk * 0.14433756729740643f - hwc[h] * pa + mterm;
    }
  }
  __syncthreads();

  // phase 3: softmax per h (32 lanes per h); write exp (unnormalized) to attnb bf16; rinv[h]=1/sum
  if (tid < 384) {
    int h = tid >> 5, g = tid & 31;
    float4 vals[4];
    float mx = -1e30f;
    #pragma unroll
    for (int it = 0; it < 4; it++) {
      vals[it] = *(const float4*)&logits[h][it * 128 + g * 4];
      mx = fmaxf(mx, fmaxf(fmaxf(vals[it].x, vals[it].y), fmaxf(vals[it].z, vals[it].w)));
    }
    #pragma unroll
    for (int off = 16; off > 0; off >>= 1) mx = fmaxf(mx, __shfl_xor(mx, off, 32));
    float sum = 0.f;
    #pragma unroll
    for (int it = 0; it < 4; it++) {
      float4 e;
      e.x = __expf(vals[it].x - mx); e.y = __expf(vals[it].y - mx);
      e.z = __expf(vals[it].z - mx); e.w = __expf(vals[it].w - mx);
      sum += e.x + e.y + e.z + e.w;
      ushort4 ob;
      ob.x = f2b(e.x); ob.y = f2b(e.y); ob.z = f2b(e.z); ob.w = f2b(e.w);
      int j4 = it * 128 + g * 4;
      int byte = (h * 1024 + j4 * 2) ^ ((h & 7) << 4);
      *(ushort4*)((char*)attnb + byte) = ob;
    }
    #pragma unroll
    for (int off = 16; off > 0; off >>= 1) sum += __shfl_xor(sum, off, 32);
    if (g == 0) rinv[h] = 1.0f / sum;
  }
  __syncthreads();

  size_t fb = (size_t)bi * 2112;

  // phase 5a: out_pair^T = z^T @ p^T via MFMA; A-frags loaded directly from global z
  {
    int c0w = wv * 16;
    const float* zcol = zbase + c0w + lr;
    f32x4 acc = {0.f, 0.f, 0.f, 0.f};
    #pragma unroll 2
    for (int jt = 0; jt < 16; jt++) {
      int jb = jt * 32 + lk * 8;
      const float* zj = zcol + (size_t)jb * 128;
      float a0 = zj[0];
      float a1 = zj[128];
      float a2 = zj[256];
      float a3 = zj[384];
      float a4 = zj[512];
      float a5 = zj[640];
      float a6 = zj[768];
      float a7 = zj[896];
      bf16x8 afrag;
      afrag[0] = (short)f2b(a0); afrag[1] = (short)f2b(a1);
      afrag[2] = (short)f2b(a2); afrag[3] = (short)f2b(a3);
      afrag[4] = (short)f2b(a4); afrag[5] = (short)f2b(a5);
      afrag[6] = (short)f2b(a6); afrag[7] = (short)f2b(a7);
      int abyte = (lr * 1024 + jb * 2) ^ ((lr & 7) << 4);
      bf16x8 pfrag = *(const bf16x8*)((const char*)attnb + abyte);
      acc = __builtin_amdgcn_mfma_f32_16x16x32_bf16(afrag, pfrag, acc, 0, 0, 0);
    }
    if (lr < 12) {
      float rn = rinv[lr];
      ushort4 ow;
      ow.x = f2b(acc[0] * rn); ow.y = f2b(acc[1] * rn);
      ow.z = f2b(acc[2] * rn); ow.w = f2b(acc[3] * rn);
      *(ushort4*)&feats[fb + 576 + lr * 128 + c0w + lk * 4] = ow;
    }
  }

  // phase 5b: [out_scalar | rpg] = attn @ [v | vg] via MFMA over vT (L2-resident), deferred rinv
  {
    const unsigned short* vTb = vT + (size_t)b * 480 * 512;
    for (int t = wv; t < 30; t += 8) {
      int c0 = t * 16;
      const unsigned short* vrow = vTb + (size_t)(c0 + lr) * 512 + lk * 8;
      f32x4 acc = {0.f, 0.f, 0.f, 0.f};
      #pragma unroll
      for (int kc = 0; kc < 16; kc++) {
        bf16x8 bfrag = *(const bf16x8*)(vrow + kc * 32);
        int abyte = (lr * 1024 + (kc * 32 + lk * 8) * 2) ^ ((lr & 7) << 4);
        bf16x8 afrag = *(const bf16x8*)((const char*)attnb + abyte);
        acc = __builtin_amdgcn_mfma_f32_16x16x32_bf16(afrag, bfrag, acc, 0, 0, 0);
      }
      #pragma unroll
      for (int reg = 0; reg < 4; reg++) {
        int h = lk * 4 + reg;
        if (h < 12) {
          float val = acc[reg] * rinv[h];
          int c = c0 + lr;
          if (c < 192) { if ((c >> 4) == h) feats[fb + c] = f2b(val); }
          else { int r = c - 192; if (r >= h * 24 && r < h * 24 + 24) rpg_lds[r] = val; }
        }
      }
    }
  }
  __syncthreads();

  // phase 6: rpl = R^T (rpg - t), norms
  if (tid < 96) {
    int h = tid >> 3, pv = tid & 7;
    float gx = rpg_lds[h * 24 + pv * 3 + 0] - tl[0];
    float gy = rpg_lds[h * 24 + pv * 3 + 1] - tl[1];
    float gz = rpg_lds[h * 24 + pv * 3 + 2] - tl[2];
    float lx = Rl[0] * gx + Rl[3] * gy + Rl[6] * gz;
    float ly = Rl[1] * gx + Rl[4] * gy + Rl[7] * gz;
    float lz = Rl[2] * gx + Rl[5] * gy + Rl[8] * gz;
    feats[fb + 192 + tid] = f2b(lx);
    feats[fb + 288 + tid] = f2b(ly);
    feats[fb + 384 + tid] = f2b(lz);
    feats[fb + 480 + tid] = f2b(sqrtf(lx * lx + ly * ly + lz * lz + 1e-8f));
  }
}

// ---------------- K3: out = (feats @ wout + bout) * mask ----------------
__global__ __launch_bounds__(256) void k_out(const unsigned short* __restrict__ feats,
                                             const unsigned short* __restrict__ woutT,
                                             const float* __restrict__ bout,
                                             const float* __restrict__ mrow,
                                             float* __restrict__ out) {
  __shared__ unsigned short At[2048]; // [64 m][32 k] bf16 swizzled
  __shared__ unsigned short Bt[2048]; // [64 n][32 k] bf16 swizzled
  int m0 = blockIdx.x * 64, n0 = blockIdx.y * 64;
  int tid = threadIdx.x;
  int wv = tid >> 6, l = tid & 63, lr = l & 15, lk = l >> 4;
  int wm = wv >> 1, wn = wv & 1;
  f32x4 acc[2][2] = {};
  int sr = tid >> 2, sq = tid & 3;
  const char* fbase = (const char*)feats + (size_t)(m0 + sr) * 4224 + sq * 16;
  const char* bbase = (const char*)woutT + (size_t)(n0 + sr) * 4224 + sq * 16;
  int sw = ((sr * 64 + sq * 16) ^ ((sr & 7) << 4));

  uint4 av = *(const uint4*)(fbase);
  uint4 bv = *(const uint4*)(bbase);
  for (int k0 = 0; k0 < 2112; k0 += 32) {
    __syncthreads();
    *(uint4*)((char*)At + sw) = av;
    *(uint4*)((char*)Bt + sw) = bv;
    __syncthreads();
    if (k0 + 32 < 2112) {
      av = *(const uint4*)(fbase + (size_t)(k0 + 32) * 2);
      bv = *(const uint4*)(bbase + (size_t)(k0 + 32) * 2);
    }
    bf16x8 af[2], bf[2];
    #pragma unroll
    for (int mt = 0; mt < 2; mt++) {
      int row = wm * 32 + mt * 16 + lr;
      af[mt] = *(const bf16x8*)((const char*)At + ((row * 64 + lk * 16) ^ ((row & 7) << 4)));
    }
    #pragma unroll
    for (int nt = 0; nt < 2; nt++) {
      int row = wn * 32 + nt * 16 + lr;
      bf[nt] = *(const bf16x8*)((const char*)Bt + ((row * 64 + lk * 16) ^ ((row & 7) << 4)));
    }
    #pragma unroll
    for (int mt = 0; mt < 2; mt++)
      #pragma unroll
      for (int nt = 0; nt < 2; nt++)
        acc[mt][nt] = __builtin_amdgcn_mfma_f32_16x16x32_bf16(af[mt], bf[nt], acc[mt][nt], 0, 0, 0);
  }

  #pragma unroll
  for (int mt = 0; mt < 2; mt++) {
    #pragma unroll
    for (int nt = 0; nt < 2; nt++) {
      int nc = n0 + wn * 32 + nt * 16 + lr;
      float bo = bout[nc];
      #pragma unroll
      for (int reg = 0; reg < 4; reg++) {
        int rowg = m0 + wm * 32 + mt * 16 + lk * 4 + reg;
        out[(size_t)rowg * 384 + nc] = (acc[mt][nt][reg] + bo) * mrow[rowg];
      }
    }
  }
}

extern "C" void kernel_launch(void* const* d_in, const int* in_sizes, int n_in,
                              void* d_out, int out_size, void* d_ws, size_t ws_size,
                              hipStream_t stream) {
  const float* s    = (const float*)d_in[0];
  const float* z    = (const float*)d_in[1];
  const float* rot  = (const float*)d_in[2];
  const float* trn  = (const float*)d_in[3];
  const float* msk  = (const float*)d_in[4];
  const float* wq   = (const float*)d_in[5];
  const float* bq   = (const float*)d_in[6];
  const float* wkv  = (const float*)d_in[7];
  const float* bkv  = (const float*)d_in[8];
  const float* wqp  = (const float*)d_in[9];
  const float* bqp  = (const float*)d_in[10];
  const float* wkvp = (const float*)d_in[11];
  const float* bkvp = (const float*)d_in[12];
  const float* wb   = (const float*)d_in[13];
  const float* bb   = (const float*)d_in[14];
  const float* wout = (const float*)d_in[15];
  const float* bout = (const float*)d_in[16];
  const float* hwt  = (const float*)d_in[17];

  float* qws  = (float*)d_ws;                       // 196608 f32
  float* qgws = qws + 196608;                       // 147456 f32
  float* kT   = qgws + 147456;                      // 196608 f32
  float* kgT  = kT + 196608;                        // 147456 f32
  unsigned short* vT    = (unsigned short*)(kgT + 147456);  // 491520 u16
  unsigned short* feats = vT + 491520;              // 2162688 u16
  unsigned short* woutT = feats + 2162688;          // 811008 u16
  float* out = (float*)d_out;

  k_woutT<<<dim3(66, 12), dim3(256), 0, stream>>>(wout, woutT);
  k_proj<<<dim3(256), dim3(512), 0, stream>>>(s, wq, bq, wkv, bkv, wqp, bqp, wkvp, bkvp,
                                              rot, trn, qws, qgws, kT, kgT, vT);
  k_attn<<<dim3(1024), dim3(512), 0, stream>>>(z, msk, rot, trn, hwt, wb, bb,
                                               qws, qgws, kT, kgT, vT, feats);
  k_out<<<dim3(16, 6), dim3(256), 0, stream>>>(feats, woutT, bout, msk, out);
}

// Round 6
// 272.943 us; speedup vs baseline: 1.2695x; 1.1513x over previous
//
#include <hip/hip_runtime.h>

// IPA forward, MI355X. B=2,N=512,C_S=384,C_Z=128,H=12,D=16,PQ=4,PV=8,OUT_IN=2112.
// R5: launch_bounds(512,2) for ~128 VGPR cap; k/kg packed bf16 (phase-2 loads halved, unroll 4);
//     v_cvt_pk_bf16_f32 for bf16 packing; 5a unroll 4.

typedef __attribute__((ext_vector_type(8))) short bf16x8;
typedef __attribute__((ext_vector_type(4))) float f32x4;
typedef __attribute__((ext_vector_type(4))) unsigned int u32x4;
typedef __attribute__((ext_vector_type(2))) unsigned int u32x2;

__device__ __forceinline__ unsigned short f2b(float f) {
  union { float f; unsigned int u; } x; x.f = f;
  unsigned int r = (x.u + 0x7FFFu + ((x.u >> 16) & 1u)) >> 16;
  return (unsigned short)r;
}

__device__ __forceinline__ unsigned int cvtpk(float lo, float hi) {
  unsigned int r;
  asm("v_cvt_pk_bf16_f32 %0, %1, %2" : "=v"(r) : "v"(lo), "v"(hi));
  return r;
}

// ---------------- K0: wout (2112x384 f32) -> woutT (384x2112 bf16) ----------------
__global__ __launch_bounds__(256) void k_woutT(const float* __restrict__ wout,
                                               unsigned short* __restrict__ woutT) {
  __shared__ float tile[32][33];
  int kb = blockIdx.x * 32, cb = blockIdx.y * 32;
  int tx = threadIdx.x & 31, ty = threadIdx.x >> 5;
  #pragma unroll
  for (int r = ty; r < 32; r += 8) tile[r][tx] = wout[(size_t)(kb + r) * 384 + cb + tx];
  __syncthreads();
  #pragma unroll
  for (int r = ty; r < 32; r += 8) woutT[(size_t)(cb + r) * 2112 + kb + tx] = f2b(tile[tx][r]);
}

// ---------------- K1: projections + global-frame points ----------------
// qws [b*i][192] f32, qgws [b*i][144] f32,
// kpk [b][168][512] u32 (bf16 pairs): rows h*14+0..7 = k(d pairs), h*14+8..13 = kg(pc pairs)
// vT [b][480][512] bf16
__global__ __launch_bounds__(512) void k_proj(
    const float* __restrict__ s,
    const float* __restrict__ wq, const float* __restrict__ bq,
    const float* __restrict__ wkv, const float* __restrict__ bkv,
    const float* __restrict__ wqp, const float* __restrict__ bqp,
    const float* __restrict__ wkvp, const float* __restrict__ bkvp,
    const float* __restrict__ rot, const float* __restrict__ trn,
    float* __restrict__ qws, float* __restrict__ qgws,
    unsigned short* __restrict__ kpkS,
    unsigned short* __restrict__ vT) {
  __shared__ float s_lds[4 * 384];
  __shared__ float praw[4][576];
  int tid = threadIdx.x;
  int row0 = blockIdx.x * 4;

  for (int idx = tid; idx < 1536; idx += 512)
    s_lds[idx] = s[(size_t)row0 * 384 + idx];
  __syncthreads();

  int no = 0;
  const float* wpt[3]; int stv[3]; float acc[3][4];
  int ocol[3];
  for (int o = tid; o < 1152; o += 512) {
    const float* w; float bias; int ncol, col;
    if (o < 192)      { w = wq;   ncol = 192; col = o;       bias = bq[col]; }
    else if (o < 576) { w = wkv;  ncol = 384; col = o - 192; bias = bkv[col]; }
    else if (o < 720) { w = wqp;  ncol = 144; col = o - 576; bias = bqp[col]; }
    else              { w = wkvp; ncol = 432; col = o - 720; bias = bkvp[col]; }
    wpt[no] = w + col; stv[no] = ncol; ocol[no] = o;
    acc[no][0] = bias; acc[no][1] = bias; acc[no][2] = bias; acc[no][3] = bias;
    no++;
  }

  for (int kc = 0; kc < 384; kc += 8) {
    float sreg[4][8];
    #pragma unroll
    for (int r = 0; r < 4; r++) {
      float4 a = *(const float4*)&s_lds[r * 384 + kc];
      float4 b = *(const float4*)&s_lds[r * 384 + kc + 4];
      sreg[r][0] = a.x; sreg[r][1] = a.y; sreg[r][2] = a.z; sreg[r][3] = a.w;
      sreg[r][4] = b.x; sreg[r][5] = b.y; sreg[r][6] = b.z; sreg[r][7] = b.w;
    }
    for (int oi = 0; oi < no; oi++) {
      const float* wcp = wpt[oi]; int st = stv[oi];
      #pragma unroll
      for (int e = 0; e < 8; e++) {
        float wv = wcp[(size_t)(kc + e) * st];
        #pragma unroll
        for (int r = 0; r < 4; r++) acc[oi][r] += sreg[r][e] * wv;
      }
    }
  }

  for (int oi = 0; oi < no; oi++) {
    int o = ocol[oi];
    #pragma unroll
    for (int r = 0; r < 4; r++) {
      float v = acc[oi][r];
      int bi = row0 + r;
      int bb2 = bi >> 9, jj = bi & 511;
      if (o < 192) qws[(size_t)bi * 192 + o] = v;
      else if (o < 576) {
        int c = o - 192, h = c >> 5, e = c & 31;
        if (e < 16)
          kpkS[(((size_t)bb2 * 168 + h * 14 + (e >> 1)) * 512 + jj) * 2 + (e & 1)] = f2b(v);
        else
          vT[((size_t)bb2 * 480 + h * 16 + (e - 16)) * 512 + jj] = f2b(v);
      } else praw[r][o - 576] = v;
    }
  }
  __syncthreads();

  for (int idx = tid; idx < 768; idx += 512) {
    int r = idx / 192, p = idx % 192;
    int bi = row0 + r;
    int bb2 = bi >> 9, jj = bi & 511;
    const float* Rm = rot + (size_t)bi * 9;
    const float* tv = trn + (size_t)bi * 3;
    float x, y, z;
    if (p < 48) { x = praw[r][p]; y = praw[r][48 + p]; z = praw[r][96 + p]; }
    else { int q = p - 48; x = praw[r][144 + q]; y = praw[r][288 + q]; z = praw[r][432 + q]; }
    float gx = Rm[0] * x + Rm[1] * y + Rm[2] * z + tv[0];
    float gy = Rm[3] * x + Rm[4] * y + Rm[5] * z + tv[1];
    float gz = Rm[6] * x + Rm[7] * y + Rm[8] * z + tv[2];
    if (p < 48) {
      float* dst = qgws + (size_t)bi * 144 + p * 3;
      dst[0] = gx; dst[1] = gy; dst[2] = gz;
    } else {
      int q12 = p - 48; int h = q12 / 12, qq = q12 % 12;
      if (qq < 4) {
        size_t rowb = (size_t)bb2 * 168 + h * 14 + 8;
        int pc = qq * 3;
        kpkS[((rowb + ((pc + 0) >> 1)) * 512 + jj) * 2 + ((pc + 0) & 1)] = f2b(gx);
        kpkS[((rowb + ((pc + 1) >> 1)) * 512 + jj) * 2 + ((pc + 1) & 1)] = f2b(gy);
        kpkS[((rowb + ((pc + 2) >> 1)) * 512 + jj) * 2 + ((pc + 2) & 1)] = f2b(gz);
      } else {
        size_t base = ((size_t)bb2 * 480 + 192 + h * 24 + (qq - 4) * 3) * 512 + jj;
        vT[base] = f2b(gx); vT[base + 512] = f2b(gy); vT[base + 1024] = f2b(gz);
      }
    }
  }
}

// ---------------- K2: fused attention per (b,i) ----------------
__global__ __launch_bounds__(512, 2) void k_attn(
    const float* __restrict__ z, const float* __restrict__ mrow,
    const float* __restrict__ rot, const float* __restrict__ trn,
    const float* __restrict__ hwt, const float* __restrict__ wb, const float* __restrict__ bb,
    const float* __restrict__ qws, const float* __restrict__ qgws,
    const unsigned int* __restrict__ kpk,
    const unsigned short* __restrict__ vT,
    unsigned short* __restrict__ feats) {
  __shared__ float logits[12][512];          // 24KB
  __shared__ unsigned short attnb[8192];     // 16KB, swizzled [16][512] bf16 (rows 12-15 zero)
  __shared__ unsigned short wbT[16][128];    // 4KB
  __shared__ float q_lds[192], qg_lds[144], rpg_lds[288];
  __shared__ float rinv[12], hwc[12], Rl[9], tl[3], bbl[16];
  __shared__ float m_i_sh;

  int tid = threadIdx.x;
  int bi = blockIdx.x;
  int b = bi >> 9;
  const float* zbase = z + (size_t)bi * 512 * 128;
  int wv = tid >> 6, l = tid & 63, lr = l & 15, lk = l >> 4;

  // phase 0: stage per-i data; zero attnb rows 12..15
  if (tid < 192) q_lds[tid] = qws[(size_t)bi * 192 + tid];
  else if (tid < 336) qg_lds[tid - 192] = qgws[(size_t)bi * 144 + (tid - 192)];
  else if (tid < 348) {
    int h = tid - 336; float w = hwt[h];
    hwc[h] = 0.5f * logf(1.0f + __expf(w)) * 0.13608276348795434f; // 0.5*softplus*sqrt(1/54)
  }
  else if (tid >= 352 && tid < 361) Rl[tid - 352] = rot[(size_t)bi * 9 + (tid - 352)];
  else if (tid >= 364 && tid < 367) tl[tid - 364] = trn[(size_t)bi * 3 + (tid - 364)];
  else if (tid >= 368 && tid < 384) bbl[tid - 368] = ((tid - 368) < 12) ? bb[tid - 368] : 0.0f;
  else if (tid == 384) m_i_sh = mrow[bi];
  for (int idx = tid; idx < 2048; idx += 512) {
    int h = idx >> 7, c = idx & 127;
    wbT[h][c] = (h < 12) ? f2b(wb[c * 12 + h]) : (unsigned short)0;
  }
  { // zero rows 12..15 of attnb
    ushort4 zer = {0, 0, 0, 0};
    int h = 12 + (tid >> 7), j4 = (tid & 127) * 4;
    int byte = (h * 1024 + j4 * 2) ^ ((h & 7) << 4);
    *(ushort4*)((char*)attnb + byte) = zer;
  }
  __syncthreads();

  // phase 1: bias MFMA. logits[h][j] = sqrt(1/3)*(z_row . wb_col + bb)
  {
    bf16x8 bfrag[4];
    #pragma unroll
    for (int kc = 0; kc < 4; kc++)
      bfrag[kc] = *(const bf16x8*)&wbT[lr][kc * 32 + lk * 8];
    #pragma unroll 2
    for (int jt = wv; jt < 32; jt += 8) {
      f32x4 acc = {0.f, 0.f, 0.f, 0.f};
      const float4* z4 = (const float4*)(zbase + (size_t)(jt * 16 + lr) * 128);
      #pragma unroll
      for (int kc = 0; kc < 4; kc++) {
        float4 a0 = z4[kc * 8 + lk * 2 + 0];
        float4 a1 = z4[kc * 8 + lk * 2 + 1];
        u32x4 af;
        af[0] = cvtpk(a0.x, a0.y); af[1] = cvtpk(a0.z, a0.w);
        af[2] = cvtpk(a1.x, a1.y); af[3] = cvtpk(a1.z, a1.w);
        acc = __builtin_amdgcn_mfma_f32_16x16x32_bf16(__builtin_bit_cast(bf16x8, af), bfrag[kc], acc, 0, 0, 0);
      }
      if (lr < 12) {
        #pragma unroll
        for (int reg = 0; reg < 4; reg++) {
          int j = jt * 16 + lk * 4 + reg;
          logits[lr][j] = 0.5773502691896258f * (acc[reg] + bbl[lr]);
        }
      }
    }
  }
  __syncthreads();

  // phase 2: += qk*sqrt(1/48) - 0.5*hw*pa + mask. one thread per j; packed bf16 k/kg.
  {
    int j = tid;
    const unsigned int* kpb = kpk + (size_t)b * 168 * 512 + j;
    float mj = mrow[b * 512 + j];
    float mterm = 100000.0f * (m_i_sh * mj - 1.0f);
    #pragma unroll 4
    for (int h = 0; h < 12; h++) {
      const unsigned int* hp = kpb + (size_t)h * 14 * 512;
      float qk = 0.f;
      #pragma unroll
      for (int r = 0; r < 8; r++) {
        unsigned int u = hp[(size_t)r * 512];
        float f0 = __builtin_bit_cast(float, u << 16);
        float f1 = __builtin_bit_cast(float, u & 0xffff0000u);
        qk += q_lds[h * 16 + 2 * r] * f0 + q_lds[h * 16 + 2 * r + 1] * f1;
      }
      float pa = 0.f;
      #pragma unroll
      for (int r = 0; r < 6; r++) {
        unsigned int u = hp[(size_t)(8 + r) * 512];
        float f0 = __builtin_bit_cast(float, u << 16);
        float f1 = __builtin_bit_cast(float, u & 0xffff0000u);
        float d0 = qg_lds[h * 12 + 2 * r] - f0;
        float d1 = qg_lds[h * 12 + 2 * r + 1] - f1;
        pa += d0 * d0 + d1 * d1;
      }
      logits[h][j] += qk * 0.14433756729740643f - hwc[h] * pa + mterm;
    }
  }
  __syncthreads();

  // phase 3: softmax per h (32 lanes per h); write exp (unnormalized) to attnb bf16; rinv[h]=1/sum
  if (tid < 384) {
    int h = tid >> 5, g = tid & 31;
    float4 vals[4];
    float mx = -1e30f;
    #pragma unroll
    for (int it = 0; it < 4; it++) {
      vals[it] = *(const float4*)&logits[h][it * 128 + g * 4];
      mx = fmaxf(mx, fmaxf(fmaxf(vals[it].x, vals[it].y), fmaxf(vals[it].z, vals[it].w)));
    }
    #pragma unroll
    for (int off = 16; off > 0; off >>= 1) mx = fmaxf(mx, __shfl_xor(mx, off, 32));
    float sum = 0.f;
    #pragma unroll
    for (int it = 0; it < 4; it++) {
      float4 e;
      e.x = __expf(vals[it].x - mx); e.y = __expf(vals[it].y - mx);
      e.z = __expf(vals[it].z - mx); e.w = __expf(vals[it].w - mx);
      sum += e.x + e.y + e.z + e.w;
      u32x2 ob;
      ob[0] = cvtpk(e.x, e.y); ob[1] = cvtpk(e.z, e.w);
      int j4 = it * 128 + g * 4;
      int byte = (h * 1024 + j4 * 2) ^ ((h & 7) << 4);
      *(u32x2*)((char*)attnb + byte) = ob;
    }
    #pragma unroll
    for (int off = 16; off > 0; off >>= 1) sum += __shfl_xor(sum, off, 32);
    if (g == 0) rinv[h] = 1.0f / sum;
  }
  __syncthreads();

  size_t fb = (size_t)bi * 2112;

  // phase 5a: out_pair^T = z^T @ p^T via MFMA; A-frags loaded directly from global z
  {
    int c0w = wv * 16;
    const float* zcol = zbase + c0w + lr;
    f32x4 acc = {0.f, 0.f, 0.f, 0.f};
    #pragma unroll 4
    for (int jt = 0; jt < 16; jt++) {
      int jb = jt * 32 + lk * 8;
      const float* zj = zcol + (size_t)jb * 128;
      float a0 = zj[0];
      float a1 = zj[128];
      float a2 = zj[256];
      float a3 = zj[384];
      float a4 = zj[512];
      float a5 = zj[640];
      float a6 = zj[768];
      float a7 = zj[896];
      u32x4 af;
      af[0] = cvtpk(a0, a1); af[1] = cvtpk(a2, a3);
      af[2] = cvtpk(a4, a5); af[3] = cvtpk(a6, a7);
      int abyte = (lr * 1024 + jb * 2) ^ ((lr & 7) << 4);
      bf16x8 pfrag = *(const bf16x8*)((const char*)attnb + abyte);
      acc = __builtin_amdgcn_mfma_f32_16x16x32_bf16(__builtin_bit_cast(bf16x8, af), pfrag, acc, 0, 0, 0);
    }
    if (lr < 12) {
      float rn = rinv[lr];
      u32x2 ow;
      ow[0] = cvtpk(acc[0] * rn, acc[1] * rn);
      ow[1] = cvtpk(acc[2] * rn, acc[3] * rn);
      *(u32x2*)&feats[fb + 576 + lr * 128 + c0w + lk * 4] = ow;
    }
  }

  // phase 5b: [out_scalar | rpg] = attn @ [v | vg] via MFMA over vT (L2-resident), deferred rinv
  {
    const unsigned short* vTb = vT + (size_t)b * 480 * 512;
    for (int t = wv; t < 30; t += 8) {
      int c0 = t * 16;
      const unsigned short* vrow = vTb + (size_t)(c0 + lr) * 512 + lk * 8;
      f32x4 acc = {0.f, 0.f, 0.f, 0.f};
      #pragma unroll
      for (int kc = 0; kc < 16; kc++) {
        bf16x8 bfrag = *(const bf16x8*)(vrow + kc * 32);
        int abyte = (lr * 1024 + (kc * 32 + lk * 8) * 2) ^ ((lr & 7) << 4);
        bf16x8 afrag = *(const bf16x8*)((const char*)attnb + abyte);
        acc = __builtin_amdgcn_mfma_f32_16x16x32_bf16(afrag, bfrag, acc, 0, 0, 0);
      }
      #pragma unroll
      for (int reg = 0; reg < 4; reg++) {
        int h = lk * 4 + reg;
        if (h < 12) {
          float val = acc[reg] * rinv[h];
          int c = c0 + lr;
          if (c < 192) { if ((c >> 4) == h) feats[fb + c] = f2b(val); }
          else { int r = c - 192; if (r >= h * 24 && r < h * 24 + 24) rpg_lds[r] = val; }
        }
      }
    }
  }
  __syncthreads();

  // phase 6: rpl = R^T (rpg - t), norms
  if (tid < 96) {
    int h = tid >> 3, pv = tid & 7;
    float gx = rpg_lds[h * 24 + pv * 3 + 0] - tl[0];
    float gy = rpg_lds[h * 24 + pv * 3 + 1] - tl[1];
    float gz = rpg_lds[h * 24 + pv * 3 + 2] - tl[2];
    float lx = Rl[0] * gx + Rl[3] * gy + Rl[6] * gz;
    float ly = Rl[1] * gx + Rl[4] * gy + Rl[7] * gz;
    float lz = Rl[2] * gx + Rl[5] * gy + Rl[8] * gz;
    feats[fb + 192 + tid] = f2b(lx);
    feats[fb + 288 + tid] = f2b(ly);
    feats[fb + 384 + tid] = f2b(lz);
    feats[fb + 480 + tid] = f2b(sqrtf(lx * lx + ly * ly + lz * lz + 1e-8f));
  }
}

// ---------------- K3: out = (feats @ wout + bout) * mask ----------------
__global__ __launch_bounds__(256) void k_out(const unsigned short* __restrict__ feats,
                                             const unsigned short* __restrict__ woutT,
                                             const float* __restrict__ bout,
                                             const float* __restrict__ mrow,
                                             float* __restrict__ out) {
  __shared__ unsigned short At[2048]; // [64 m][32 k] bf16 swizzled
  __shared__ unsigned short Bt[2048]; // [64 n][32 k] bf16 swizzled
  int m0 = blockIdx.x * 64, n0 = blockIdx.y * 64;
  int tid = threadIdx.x;
  int wv = tid >> 6, l = tid & 63, lr = l & 15, lk = l >> 4;
  int wm = wv >> 1, wn = wv & 1;
  f32x4 acc[2][2] = {};
  int sr = tid >> 2, sq = tid & 3;
  const char* fbase = (const char*)feats + (size_t)(m0 + sr) * 4224 + sq * 16;
  const char* bbase = (const char*)woutT + (size_t)(n0 + sr) * 4224 + sq * 16;
  int sw = ((sr * 64 + sq * 16) ^ ((sr & 7) << 4));

  uint4 av = *(const uint4*)(fbase);
  uint4 bv = *(const uint4*)(bbase);
  for (int k0 = 0; k0 < 2112; k0 += 32) {
    __syncthreads();
    *(uint4*)((char*)At + sw) = av;
    *(uint4*)((char*)Bt + sw) = bv;
    __syncthreads();
    if (k0 + 32 < 2112) {
      av = *(const uint4*)(fbase + (size_t)(k0 + 32) * 2);
      bv = *(const uint4*)(bbase + (size_t)(k0 + 32) * 2);
    }
    bf16x8 af[2], bf[2];
    #pragma unroll
    for (int mt = 0; mt < 2; mt++) {
      int row = wm * 32 + mt * 16 + lr;
      af[mt] = *(const bf16x8*)((const char*)At + ((row * 64 + lk * 16) ^ ((row & 7) << 4)));
    }
    #pragma unroll
    for (int nt = 0; nt < 2; nt++) {
      int row = wn * 32 + nt * 16 + lr;
      bf[nt] = *(const bf16x8*)((const char*)Bt + ((row * 64 + lk * 16) ^ ((row & 7) << 4)));
    }
    #pragma unroll
    for (int mt = 0; mt < 2; mt++)
      #pragma unroll
      for (int nt = 0; nt < 2; nt++)
        acc[mt][nt] = __builtin_amdgcn_mfma_f32_16x16x32_bf16(af[mt], bf[nt], acc[mt][nt], 0, 0, 0);
  }

  #pragma unroll
  for (int mt = 0; mt < 2; mt++) {
    #pragma unroll
    for (int nt = 0; nt < 2; nt++) {
      int nc = n0 + wn * 32 + nt * 16 + lr;
      float bo = bout[nc];
      #pragma unroll
      for (int reg = 0; reg < 4; reg++) {
        int rowg = m0 + wm * 32 + mt * 16 + lk * 4 + reg;
        out[(size_t)rowg * 384 + nc] = (acc[mt][nt][reg] + bo) * mrow[rowg];
      }
    }
  }
}

extern "C" void kernel_launch(void* const* d_in, const int* in_sizes, int n_in,
                              void* d_out, int out_size, void* d_ws, size_t ws_size,
                              hipStream_t stream) {
  const float* s    = (const float*)d_in[0];
  const float* z    = (const float*)d_in[1];
  const float* rot  = (const float*)d_in[2];
  const float* trn  = (const float*)d_in[3];
  const float* msk  = (const float*)d_in[4];
  const float* wq   = (const float*)d_in[5];
  const float* bq   = (const float*)d_in[6];
  const float* wkv  = (const float*)d_in[7];
  const float* bkv  = (const float*)d_in[8];
  const float* wqp  = (const float*)d_in[9];
  const float* bqp  = (const float*)d_in[10];
  const float* wkvp = (const float*)d_in[11];
  const float* bkvp = (const float*)d_in[12];
  const float* wb   = (const float*)d_in[13];
  const float* bb   = (const float*)d_in[14];
  const float* wout = (const float*)d_in[15];
  const float* bout = (const float*)d_in[16];
  const float* hwt  = (const float*)d_in[17];

  float* qws  = (float*)d_ws;                              // 196608 f32
  float* qgws = qws + 196608;                              // 147456 f32
  unsigned int* kpk = (unsigned int*)(qgws + 147456);      // 172032 u32
  unsigned short* vT    = (unsigned short*)(kpk + 172032); // 491520 u16
  unsigned short* feats = vT + 491520;                     // 2162688 u16
  unsigned short* woutT = feats + 2162688;                 // 811008 u16
  float* out = (float*)d_out;

  k_woutT<<<dim3(66, 12), dim3(256), 0, stream>>>(wout, woutT);
  k_proj<<<dim3(256), dim3(512), 0, stream>>>(s, wq, bq, wkv, bkv, wqp, bqp, wkvp, bkvp,
                                              rot, trn, qws, qgws, (unsigned short*)kpk, vT);
  k_attn<<<dim3(1024), dim3(512), 0, stream>>>(z, msk, rot, trn, hwt, wb, bb,
                                               qws, qgws, kpk, vT, feats);
  k_out<<<dim3(16, 6), dim3(256), 0, stream>>>(feats, woutT, bout, msk, out);
}

// Round 7
// 252.931 us; speedup vs baseline: 1.3700x; 1.0791x over previous
//
#include <hip/hip_runtime.h>

// IPA forward, MI355X. B=2,N=512,C_S=384,C_Z=128,H=12,D=16,PQ=4,PV=8,OUT_IN=2112.
// R6: lift shared-panel phases out of per-i kernel:
//     k_qkpa: qk+pa logits via per-(b,h) MFMA GEMM (K=32, |qg-kg|^2 expansion, hi/lo bf16 splits)
//     k_av:   out_scalar+rpg via per-(b,h) MFMA GEMM over normalized attn, + rpl/norm epilogue
//     k_attn: bias MFMA (z HBM) + qkpa add + softmax (writes attn bf16 global+LDS) + out_pair (z L3)

typedef __attribute__((ext_vector_type(8))) short bf16x8;
typedef __attribute__((ext_vector_type(4))) float f32x4;
typedef __attribute__((ext_vector_type(4))) unsigned int u32x4;
typedef __attribute__((ext_vector_type(2))) unsigned int u32x2;

__device__ __forceinline__ unsigned short f2b(float f) {
  union { float f; unsigned int u; } x; x.f = f;
  unsigned int r = (x.u + 0x7FFFu + ((x.u >> 16) & 1u)) >> 16;
  return (unsigned short)r;
}
__device__ __forceinline__ float b2f(unsigned short u) {
  return __builtin_bit_cast(float, (unsigned int)u << 16);
}
__device__ __forceinline__ unsigned int cvtpk(float lo, float hi) {
  unsigned int r;
  asm("v_cvt_pk_bf16_f32 %0, %1, %2" : "=v"(r) : "v"(lo), "v"(hi));
  return r;
}

// ---------------- K0: wout (2112x384 f32) -> woutT (384x2112 bf16) ----------------
__global__ __launch_bounds__(256) void k_woutT(const float* __restrict__ wout,
                                               unsigned short* __restrict__ woutT) {
  __shared__ float tile[32][33];
  int kb = blockIdx.x * 32, cb = blockIdx.y * 32;
  int tx = threadIdx.x & 31, ty = threadIdx.x >> 5;
  #pragma unroll
  for (int r = ty; r < 32; r += 8) tile[r][tx] = wout[(size_t)(kb + r) * 384 + cb + tx];
  __syncthreads();
  #pragma unroll
  for (int r = ty; r < 32; r += 8) woutT[(size_t)(cb + r) * 2112 + kb + tx] = f2b(tile[tx][r]);
}

// ---------------- K1: projections + global-frame points ----------------
// qws [bi][192] f32, qgws [bi][144] f32, qnws [bi][12] f32 (|qg|^2 per h),
// kb2 [b][h][512 j][40] bf16: 0..15 k_d, 16..27 kg_pc, 28/29 hi/lo(-hwc*|kg|^2), 30/31 = 1.0
// vT [b][480][512] bf16 (rows h*16+d = v; 192+h*24+pc = vg)
__global__ __launch_bounds__(512) void k_proj(
    const float* __restrict__ s,
    const float* __restrict__ wq, const float* __restrict__ bq,
    const float* __restrict__ wkv, const float* __restrict__ bkv,
    const float* __restrict__ wqp, const float* __restrict__ bqp,
    const float* __restrict__ wkvp, const float* __restrict__ bkvp,
    const float* __restrict__ rot, const float* __restrict__ trn,
    const float* __restrict__ hwt,
    float* __restrict__ qws, float* __restrict__ qgws, float* __restrict__ qnws,
    unsigned short* __restrict__ kb2,
    unsigned short* __restrict__ vT) {
  __shared__ float s_lds[4 * 384];
  __shared__ float praw[4][576];
  int tid = threadIdx.x;
  int row0 = blockIdx.x * 4;

  for (int idx = tid; idx < 1536; idx += 512)
    s_lds[idx] = s[(size_t)row0 * 384 + idx];
  __syncthreads();

  int no = 0;
  const float* wpt[3]; int stv[3]; float acc[3][4];
  int ocol[3];
  for (int o = tid; o < 1152; o += 512) {
    const float* w; float bias; int ncol, col;
    if (o < 192)      { w = wq;   ncol = 192; col = o;       bias = bq[col]; }
    else if (o < 576) { w = wkv;  ncol = 384; col = o - 192; bias = bkv[col]; }
    else if (o < 720) { w = wqp;  ncol = 144; col = o - 576; bias = bqp[col]; }
    else              { w = wkvp; ncol = 432; col = o - 720; bias = bkvp[col]; }
    wpt[no] = w + col; stv[no] = ncol; ocol[no] = o;
    acc[no][0] = bias; acc[no][1] = bias; acc[no][2] = bias; acc[no][3] = bias;
    no++;
  }

  for (int kc = 0; kc < 384; kc += 8) {
    float sreg[4][8];
    #pragma unroll
    for (int r = 0; r < 4; r++) {
      float4 a = *(const float4*)&s_lds[r * 384 + kc];
      float4 b = *(const float4*)&s_lds[r * 384 + kc + 4];
      sreg[r][0] = a.x; sreg[r][1] = a.y; sreg[r][2] = a.z; sreg[r][3] = a.w;
      sreg[r][4] = b.x; sreg[r][5] = b.y; sreg[r][6] = b.z; sreg[r][7] = b.w;
    }
    for (int oi = 0; oi < no; oi++) {
      const float* wcp = wpt[oi]; int st = stv[oi];
      #pragma unroll
      for (int e = 0; e < 8; e++) {
        float wv = wcp[(size_t)(kc + e) * st];
        #pragma unroll
        for (int r = 0; r < 4; r++) acc[oi][r] += sreg[r][e] * wv;
      }
    }
  }

  for (int oi = 0; oi < no; oi++) {
    int o = ocol[oi];
    #pragma unroll
    for (int r = 0; r < 4; r++) {
      float v = acc[oi][r];
      int bi = row0 + r;
      int bb2 = bi >> 9, jj = bi & 511;
      if (o < 192) qws[(size_t)bi * 192 + o] = v;
      else if (o < 576) {
        int c = o - 192, h = c >> 5, e = c & 31;
        if (e < 16)
          kb2[(((size_t)bb2 * 12 + h) * 512 + jj) * 40 + e] = f2b(v);
        else
          vT[((size_t)bb2 * 480 + h * 16 + (e - 16)) * 512 + jj] = f2b(v);
      } else praw[r][o - 576] = v;
    }
  }
  __syncthreads();

  // point transforms: per row 192 points (48 qp + 144 kvp)
  for (int idx = tid; idx < 768; idx += 512) {
    int r = idx / 192, p = idx % 192;
    int bi = row0 + r;
    int bb2 = bi >> 9, jj = bi & 511;
    const float* Rm = rot + (size_t)bi * 9;
    const float* tv = trn + (size_t)bi * 3;
    float x, y, z;
    if (p < 48) { x = praw[r][p]; y = praw[r][48 + p]; z = praw[r][96 + p]; }
    else { int q = p - 48; x = praw[r][144 + q]; y = praw[r][288 + q]; z = praw[r][432 + q]; }
    float gx = Rm[0] * x + Rm[1] * y + Rm[2] * z + tv[0];
    float gy = Rm[3] * x + Rm[4] * y + Rm[5] * z + tv[1];
    float gz = Rm[6] * x + Rm[7] * y + Rm[8] * z + tv[2];
    if (p < 48) {
      float* dst = qgws + (size_t)bi * 144 + p * 3;
      dst[0] = gx; dst[1] = gy; dst[2] = gz;
    } else {
      int q12 = p - 48; int h = q12 / 12, qq = q12 % 12;
      if (qq < 4) {
        size_t base = (((size_t)bb2 * 12 + h) * 512 + jj) * 40 + 16 + qq * 3;
        kb2[base + 0] = f2b(gx); kb2[base + 1] = f2b(gy); kb2[base + 2] = f2b(gz);
      } else {
        size_t base = ((size_t)bb2 * 480 + 192 + h * 24 + (qq - 4) * 3) * 512 + jj;
        vT[base] = f2b(gx); vT[base + 512] = f2b(gy); vT[base + 1024] = f2b(gz);
      }
    }
  }

  // per-(r,h): |qg|^2, -hwc*|kg|^2 hi/lo, ones rows (deterministic recompute, no atomics)
  if (tid < 48) {
    int r = tid / 12, h = tid % 12;
    int bi = row0 + r;
    int bb2 = bi >> 9, jj = bi & 511;
    const float* Rm = rot + (size_t)bi * 9;
    const float* tv = trn + (size_t)bi * 3;
    float hw = 0.5f * logf(1.0f + __expf(hwt[h])) * 0.13608276348795434f;
    float qn = 0.f, kn = 0.f;
    #pragma unroll
    for (int qq = 0; qq < 4; qq++) {
      { // qp point h*4+qq
        int p = h * 4 + qq;
        float x = praw[r][p], y = praw[r][48 + p], z = praw[r][96 + p];
        float gx = Rm[0]*x + Rm[1]*y + Rm[2]*z + tv[0];
        float gy = Rm[3]*x + Rm[4]*y + Rm[5]*z + tv[1];
        float gz = Rm[6]*x + Rm[7]*y + Rm[8]*z + tv[2];
        qn += gx*gx + gy*gy + gz*gz;
      }
      { // kg point: kvp (h, qq)
        int q = h * 12 + qq;
        float x = praw[r][144 + q], y = praw[r][288 + q], z = praw[r][432 + q];
        float gx = Rm[0]*x + Rm[1]*y + Rm[2]*z + tv[0];
        float gy = Rm[3]*x + Rm[4]*y + Rm[5]*z + tv[1];
        float gz = Rm[6]*x + Rm[7]*y + Rm[8]*z + tv[2];
        kn += gx*gx + gy*gy + gz*gz;
      }
    }
    qnws[(size_t)bi * 12 + h] = qn;
    float pr = -hw * kn;
    unsigned short hi = f2b(pr);
    unsigned short lo = f2b(pr - b2f(hi));
    size_t base = (((size_t)bb2 * 12 + h) * 512 + jj) * 40;
    kb2[base + 28] = hi; kb2[base + 29] = lo;
    kb2[base + 30] = 0x3F80; kb2[base + 31] = 0x3F80;
  }
}

// ---------------- K2: qkpa[bi][h][j] = qk*sqrt(1/48) - hwc*pa, per-(b,h) GEMM ----------------
__global__ __launch_bounds__(256) void k_qkpa(
    const float* __restrict__ qws, const float* __restrict__ qgws,
    const float* __restrict__ qnws, const float* __restrict__ hwt,
    const unsigned short* __restrict__ kb2,
    float* __restrict__ qkpa) {
  __shared__ unsigned short aq[128 * 40]; // [128 i][40 k] bf16, 80B rows
  int bh = blockIdx.x;
  int b = bh / 12, h = bh - b * 12;
  int i0 = blockIdx.y * 128;
  int tid = threadIdx.x;
  float hw = 0.5f * logf(1.0f + __expf(hwt[h])) * 0.13608276348795434f;

  {
    int r = tid >> 1, c0 = (tid & 1) * 20;
    size_t gi = (size_t)b * 512 + i0 + r;
    const float* qr = qws + gi * 192 + h * 16;
    const float* gr = qgws + gi * 144 + h * 12;
    float pr = -hw * qnws[gi * 12 + h];
    unsigned short hi = f2b(pr);
    unsigned short lo = f2b(pr - b2f(hi));
    for (int c = c0; c < c0 + 20; c++) {
      unsigned short v;
      if (c < 16)      v = f2b(0.14433756729740643f * qr[c]);
      else if (c < 28) v = f2b(2.0f * hw * gr[c - 16]);
      else if (c < 30) v = 0x3F80;
      else if (c == 30) v = hi;
      else              v = lo;
      aq[r * 40 + c] = v;
    }
  }
  __syncthreads();

  int w = tid >> 6, l = tid & 63, lr = l & 15, lk = l >> 4;
  int n0 = w * 128;
  bf16x8 afr[8];
  #pragma unroll
  for (int mf = 0; mf < 8; mf++)
    afr[mf] = *(const bf16x8*)&aq[(mf * 16 + lr) * 40 + lk * 8];
  const unsigned short* kbb = kb2 + (size_t)bh * 512 * 40;
  #pragma unroll 2
  for (int nf = 0; nf < 8; nf++) {
    int j = n0 + nf * 16 + lr;
    bf16x8 bfr = *(const bf16x8*)(kbb + (size_t)j * 40 + lk * 8);
    #pragma unroll
    for (int mf = 0; mf < 8; mf++) {
      f32x4 acc = {0.f, 0.f, 0.f, 0.f};
      acc = __builtin_amdgcn_mfma_f32_16x16x32_bf16(afr[mf], bfr, acc, 0, 0, 0);
      #pragma unroll
      for (int r = 0; r < 4; r++) {
        int i = i0 + mf * 16 + lk * 4 + r;
        qkpa[((size_t)(b * 512 + i) * 12 + h) * 512 + n0 + nf * 16 + lr] = acc[r];
      }
    }
  }
}

// ---------------- K3: fused attention per (b,i): bias + qkpa + softmax + out_pair ----------------
__global__ __launch_bounds__(512, 2) void k_attn(
    const float* __restrict__ z, const float* __restrict__ mrow,
    const float* __restrict__ wb, const float* __restrict__ bb,
    const float* __restrict__ qkpa,
    unsigned short* __restrict__ attnG,
    unsigned short* __restrict__ feats) {
  __shared__ float logits[12][512];          // 24KB
  __shared__ unsigned short attnb[8192];     // 16KB swizzled [16][512] bf16 (rows 12-15 zero)
  __shared__ unsigned short wbT[16][128];    // 4KB
  __shared__ float bbl[16];
  __shared__ float m_i_sh;

  int tid = threadIdx.x;
  int bi = blockIdx.x;
  int b = bi >> 9;
  const float* zbase = z + (size_t)bi * 512 * 128;
  int wv = tid >> 6, l = tid & 63, lr = l & 15, lk = l >> 4;

  // phase 0
  if (tid < 16) bbl[tid] = (tid < 12) ? bb[tid] : 0.0f;
  else if (tid == 16) m_i_sh = mrow[bi];
  for (int idx = tid; idx < 2048; idx += 512) {
    int h = idx >> 7, c = idx & 127;
    wbT[h][c] = (h < 12) ? f2b(wb[c * 12 + h]) : (unsigned short)0;
  }
  {
    ushort4 zer = {0, 0, 0, 0};
    int h = 12 + (tid >> 7), j4 = (tid & 127) * 4;
    int byte = (h * 1024 + j4 * 2) ^ ((h & 7) << 4);
    *(ushort4*)((char*)attnb + byte) = zer;
  }
  __syncthreads();

  // phase 1: bias MFMA. logits[h][j] = sqrt(1/3)*(z_row . wb_col + bb)
  {
    bf16x8 bfrag[4];
    #pragma unroll
    for (int kc = 0; kc < 4; kc++)
      bfrag[kc] = *(const bf16x8*)&wbT[lr][kc * 32 + lk * 8];
    #pragma unroll 2
    for (int jt = wv; jt < 32; jt += 8) {
      f32x4 acc = {0.f, 0.f, 0.f, 0.f};
      const float4* z4 = (const float4*)(zbase + (size_t)(jt * 16 + lr) * 128);
      #pragma unroll
      for (int kc = 0; kc < 4; kc++) {
        float4 a0 = z4[kc * 8 + lk * 2 + 0];
        float4 a1 = z4[kc * 8 + lk * 2 + 1];
        u32x4 af;
        af[0] = cvtpk(a0.x, a0.y); af[1] = cvtpk(a0.z, a0.w);
        af[2] = cvtpk(a1.x, a1.y); af[3] = cvtpk(a1.z, a1.w);
        acc = __builtin_amdgcn_mfma_f32_16x16x32_bf16(__builtin_bit_cast(bf16x8, af), bfrag[kc], acc, 0, 0, 0);
      }
      if (lr < 12) {
        #pragma unroll
        for (int reg = 0; reg < 4; reg++) {
          int j = jt * 16 + lk * 4 + reg;
          logits[lr][j] = 0.5773502691896258f * (acc[reg] + bbl[lr]);
        }
      }
    }
  }
  __syncthreads();

  // phase 2: += qkpa + mask term (3 float4 per thread)
  {
    const float* qb = qkpa + (size_t)bi * 12 * 512;
    float mi = m_i_sh;
    #pragma unroll
    for (int p = 0; p < 3; p++) {
      int flat = p * 2048 + tid * 4;
      int h = flat >> 9, j4 = flat & 511;
      float4 q4 = *(const float4*)(qb + flat);
      float4 m4 = *(const float4*)(mrow + b * 512 + j4);
      logits[h][j4 + 0] += q4.x + 100000.0f * (mi * m4.x - 1.0f);
      logits[h][j4 + 1] += q4.y + 100000.0f * (mi * m4.y - 1.0f);
      logits[h][j4 + 2] += q4.z + 100000.0f * (mi * m4.z - 1.0f);
      logits[h][j4 + 3] += q4.w + 100000.0f * (mi * m4.w - 1.0f);
    }
  }
  __syncthreads();

  // phase 3: softmax per h; write NORMALIZED bf16 attn to attnb (swizzled LDS) and attnG (global)
  if (tid < 384) {
    int h = tid >> 5, g = tid & 31;
    float4 vals[4];
    float mx = -1e30f;
    #pragma unroll
    for (int it = 0; it < 4; it++) {
      vals[it] = *(const float4*)&logits[h][it * 128 + g * 4];
      mx = fmaxf(mx, fmaxf(fmaxf(vals[it].x, vals[it].y), fmaxf(vals[it].z, vals[it].w)));
    }
    #pragma unroll
    for (int off = 16; off > 0; off >>= 1) mx = fmaxf(mx, __shfl_xor(mx, off, 32));
    float sum = 0.f;
    #pragma unroll
    for (int it = 0; it < 4; it++) {
      vals[it].x = __expf(vals[it].x - mx); vals[it].y = __expf(vals[it].y - mx);
      vals[it].z = __expf(vals[it].z - mx); vals[it].w = __expf(vals[it].w - mx);
      sum += vals[it].x + vals[it].y + vals[it].z + vals[it].w;
    }
    #pragma unroll
    for (int off = 16; off > 0; off >>= 1) sum += __shfl_xor(sum, off, 32);
    float rn = 1.0f / sum;
    unsigned short* gout = attnG + (((size_t)(b * 12 + h) * 512) + (bi & 511)) * 512;
    #pragma unroll
    for (int it = 0; it < 4; it++) {
      u32x2 ob;
      ob[0] = cvtpk(vals[it].x * rn, vals[it].y * rn);
      ob[1] = cvtpk(vals[it].z * rn, vals[it].w * rn);
      int j4 = it * 128 + g * 4;
      int byte = (h * 1024 + j4 * 2) ^ ((h & 7) << 4);
      *(u32x2*)((char*)attnb + byte) = ob;
      *(u32x2*)(gout + j4) = ob;
    }
  }
  __syncthreads();

  size_t fb = (size_t)bi * 2112;

  // phase 4: out_pair^T = z^T @ attn^T via MFMA; A-frags from global z (L3 second pass)
  {
    int c0w = wv * 16;
    const float* zcol = zbase + c0w + lr;
    f32x4 acc = {0.f, 0.f, 0.f, 0.f};
    #pragma unroll 4
    for (int jt = 0; jt < 16; jt++) {
      int jb = jt * 32 + lk * 8;
      const float* zj = zcol + (size_t)jb * 128;
      float a0 = zj[0];
      float a1 = zj[128];
      float a2 = zj[256];
      float a3 = zj[384];
      float a4 = zj[512];
      float a5 = zj[640];
      float a6 = zj[768];
      float a7 = zj[896];
      u32x4 af;
      af[0] = cvtpk(a0, a1); af[1] = cvtpk(a2, a3);
      af[2] = cvtpk(a4, a5); af[3] = cvtpk(a6, a7);
      int abyte = (lr * 1024 + jb * 2) ^ ((lr & 7) << 4);
      bf16x8 pfrag = *(const bf16x8*)((const char*)attnb + abyte);
      acc = __builtin_amdgcn_mfma_f32_16x16x32_bf16(__builtin_bit_cast(bf16x8, af), pfrag, acc, 0, 0, 0);
    }
    if (lr < 12) {
      u32x2 ow;
      ow[0] = cvtpk(acc[0], acc[1]);
      ow[1] = cvtpk(acc[2], acc[3]);
      *(u32x2*)&feats[fb + 576 + lr * 128 + c0w + lk * 4] = ow;
    }
  }
}

// ---------------- K4: [out_scalar | rpg] per-(b,h) GEMM + rpl/norm epilogue ----------------
__global__ __launch_bounds__(256) void k_av(
    const unsigned short* __restrict__ attnG, const unsigned short* __restrict__ vT,
    const float* __restrict__ rot, const float* __restrict__ trn,
    unsigned short* __restrict__ feats) {
  __shared__ float sc[128 * 24];
  __shared__ float rotL[128 * 9];
  __shared__ float trnL[128 * 3];
  int bh = blockIdx.x;
  int b = bh / 12, h = bh - b * 12;
  int i0 = blockIdx.y * 128;
  int tid = threadIdx.x;

  for (int idx = tid; idx < 1152; idx += 256) rotL[idx] = rot[((size_t)b * 512 + i0) * 9 + idx];
  for (int idx = tid; idx < 384; idx += 256) trnL[idx] = trn[((size_t)b * 512 + i0) * 3 + idx];

  int w = tid >> 6, l = tid & 63, lr = l & 15, lk = l >> 4;
  int iw = w * 32;
  const unsigned short* Abase = attnG + ((size_t)bh * 512 + i0 + iw) * 512;
  const unsigned short* vTb = vT + (size_t)b * 480 * 512;
  int cm[3];
  #pragma unroll
  for (int nf = 0; nf < 3; nf++) {
    int c = nf * 16 + lr;
    cm[nf] = (c < 16) ? (h * 16 + c) : (c < 40 ? 192 + h * 24 + (c - 16) : 0);
  }
  f32x4 acc[2][3] = {};
  #pragma unroll 2
  for (int jb = 0; jb < 512; jb += 32) {
    bf16x8 a0 = *(const bf16x8*)(Abase + (size_t)lr * 512 + jb + lk * 8);
    bf16x8 a1 = *(const bf16x8*)(Abase + (size_t)(16 + lr) * 512 + jb + lk * 8);
    #pragma unroll
    for (int nf = 0; nf < 3; nf++) {
      bf16x8 bfr = *(const bf16x8*)(vTb + (size_t)cm[nf] * 512 + jb + lk * 8);
      acc[0][nf] = __builtin_amdgcn_mfma_f32_16x16x32_bf16(a0, bfr, acc[0][nf], 0, 0, 0);
      acc[1][nf] = __builtin_amdgcn_mfma_f32_16x16x32_bf16(a1, bfr, acc[1][nf], 0, 0, 0);
    }
  }
  #pragma unroll
  for (int mf = 0; mf < 2; mf++) {
    #pragma unroll
    for (int nf = 0; nf < 3; nf++) {
      int c = nf * 16 + lr;
      #pragma unroll
      for (int r = 0; r < 4; r++) {
        int il = iw + mf * 16 + lk * 4 + r;
        float v = acc[mf][nf][r];
        if (c < 16) feats[(size_t)(b * 512 + i0 + il) * 2112 + h * 16 + c] = f2b(v);
        else if (c < 40) sc[il * 24 + (c - 16)] = v;
      }
    }
  }
  __syncthreads();
  #pragma unroll
  for (int k2 = 0; k2 < 4; k2++) {
    int itm = tid + k2 * 256;
    int il = itm >> 3, pv = itm & 7;
    float gx = sc[il * 24 + pv * 3 + 0] - trnL[il * 3 + 0];
    float gy = sc[il * 24 + pv * 3 + 1] - trnL[il * 3 + 1];
    float gz = sc[il * 24 + pv * 3 + 2] - trnL[il * 3 + 2];
    const float* R = &rotL[il * 9];
    float lx = R[0] * gx + R[3] * gy + R[6] * gz;
    float ly = R[1] * gx + R[4] * gy + R[7] * gz;
    float lz = R[2] * gx + R[5] * gy + R[8] * gz;
    size_t fb = (size_t)(b * 512 + i0 + il) * 2112;
    feats[fb + 192 + h * 8 + pv] = f2b(lx);
    feats[fb + 288 + h * 8 + pv] = f2b(ly);
    feats[fb + 384 + h * 8 + pv] = f2b(lz);
    feats[fb + 480 + h * 8 + pv] = f2b(sqrtf(lx * lx + ly * ly + lz * lz + 1e-8f));
  }
}

// ---------------- K5: out = (feats @ wout + bout) * mask ----------------
__global__ __launch_bounds__(256) void k_out(const unsigned short* __restrict__ feats,
                                             const unsigned short* __restrict__ woutT,
                                             const float* __restrict__ bout,
                                             const float* __restrict__ mrow,
                                             float* __restrict__ out) {
  __shared__ unsigned short At[2048];
  __shared__ unsigned short Bt[2048];
  int m0 = blockIdx.x * 64, n0 = blockIdx.y * 64;
  int tid = threadIdx.x;
  int wv = tid >> 6, l = tid & 63, lr = l & 15, lk = l >> 4;
  int wm = wv >> 1, wn = wv & 1;
  f32x4 acc[2][2] = {};
  int sr = tid >> 2, sq = tid & 3;
  const char* fbase = (const char*)feats + (size_t)(m0 + sr) * 4224 + sq * 16;
  const char* bbase = (const char*)woutT + (size_t)(n0 + sr) * 4224 + sq * 16;
  int sw = ((sr * 64 + sq * 16) ^ ((sr & 7) << 4));

  uint4 av = *(const uint4*)(fbase);
  uint4 bv = *(const uint4*)(bbase);
  for (int k0 = 0; k0 < 2112; k0 += 32) {
    __syncthreads();
    *(uint4*)((char*)At + sw) = av;
    *(uint4*)((char*)Bt + sw) = bv;
    __syncthreads();
    if (k0 + 32 < 2112) {
      av = *(const uint4*)(fbase + (size_t)(k0 + 32) * 2);
      bv = *(const uint4*)(bbase + (size_t)(k0 + 32) * 2);
    }
    bf16x8 af[2], bf[2];
    #pragma unroll
    for (int mt = 0; mt < 2; mt++) {
      int row = wm * 32 + mt * 16 + lr;
      af[mt] = *(const bf16x8*)((const char*)At + ((row * 64 + lk * 16) ^ ((row & 7) << 4)));
    }
    #pragma unroll
    for (int nt = 0; nt < 2; nt++) {
      int row = wn * 32 + nt * 16 + lr;
      bf[nt] = *(const bf16x8*)((const char*)Bt + ((row * 64 + lk * 16) ^ ((row & 7) << 4)));
    }
    #pragma unroll
    for (int mt = 0; mt < 2; mt++)
      #pragma unroll
      for (int nt = 0; nt < 2; nt++)
        acc[mt][nt] = __builtin_amdgcn_mfma_f32_16x16x32_bf16(af[mt], bf[nt], acc[mt][nt], 0, 0, 0);
  }

  #pragma unroll
  for (int mt = 0; mt < 2; mt++) {
    #pragma unroll
    for (int nt = 0; nt < 2; nt++) {
      int nc = n0 + wn * 32 + nt * 16 + lr;
      float bo = bout[nc];
      #pragma unroll
      for (int reg = 0; reg < 4; reg++) {
        int rowg = m0 + wm * 32 + mt * 16 + lk * 4 + reg;
        out[(size_t)rowg * 384 + nc] = (acc[mt][nt][reg] + bo) * mrow[rowg];
      }
    }
  }
}

extern "C" void kernel_launch(void* const* d_in, const int* in_sizes, int n_in,
                              void* d_out, int out_size, void* d_ws, size_t ws_size,
                              hipStream_t stream) {
  const float* s    = (const float*)d_in[0];
  const float* z    = (const float*)d_in[1];
  const float* rot  = (const float*)d_in[2];
  const float* trn  = (const float*)d_in[3];
  const float* msk  = (const float*)d_in[4];
  const float* wq   = (const float*)d_in[5];
  const float* bq   = (const float*)d_in[6];
  const float* wkv  = (const float*)d_in[7];
  const float* bkv  = (const float*)d_in[8];
  const float* wqp  = (const float*)d_in[9];
  const float* bqp  = (const float*)d_in[10];
  const float* wkvp = (const float*)d_in[11];
  const float* bkvp = (const float*)d_in[12];
  const float* wb   = (const float*)d_in[13];
  const float* bb   = (const float*)d_in[14];
  const float* wout = (const float*)d_in[15];
  const float* bout = (const float*)d_in[16];
  const float* hwt  = (const float*)d_in[17];

  float* qws  = (float*)d_ws;                               // 196608 f32
  float* qgws = qws + 196608;                               // 147456 f32
  float* qnws = qgws + 147456;                              // 12288 f32
  float* qkpa = qnws + 12288;                               // 6291456 f32
  unsigned short* vT    = (unsigned short*)(qkpa + 6291456); // 491520 u16
  unsigned short* kb2   = vT + 491520;                      // 491520 u16
  unsigned short* attnG = kb2 + 491520;                     // 6291456 u16
  unsigned short* feats = attnG + 6291456;                  // 2162688 u16
  unsigned short* woutT = feats + 2162688;                  // 811008 u16
  float* out = (float*)d_out;

  k_woutT<<<dim3(66, 12), dim3(256), 0, stream>>>(wout, woutT);
  k_proj<<<dim3(256), dim3(512), 0, stream>>>(s, wq, bq, wkv, bkv, wqp, bqp, wkvp, bkvp,
                                              rot, trn, hwt, qws, qgws, qnws, kb2, vT);
  k_qkpa<<<dim3(24, 4), dim3(256), 0, stream>>>(qws, qgws, qnws, hwt, kb2, qkpa);
  k_attn<<<dim3(1024), dim3(512), 0, stream>>>(z, msk, wb, bb, qkpa, attnG, feats);
  k_av<<<dim3(24, 4), dim3(256), 0, stream>>>(attnG, vT, rot, trn, feats);
  k_out<<<dim3(16, 6), dim3(256), 0, stream>>>(feats, woutT, bout, msk, out);
}